// Round 7
// baseline (153.469 us; speedup 1.0000x reference)
//
#include <hip/hip_runtime.h>
#include <math.h>

#define SC 4
#define BB 2
#define CC 32
#define HH 256
#define WW 512
#define CH (HH / SC)   // 64
#define CW (WW / SC)   // 128

using f16x8 = __attribute__((ext_vector_type(8))) _Float16;
using f32x4 = __attribute__((ext_vector_type(4))) float;
using f32x2 = __attribute__((ext_vector_type(2))) float;

// Direction metadata (output channel order: c, l, r, t, b, lt, rt, lb, rb)
//   s0: 0 -> xv (x[w%4]), 1 -> 4-(w%4) (D1), 2 -> (w%4)+1 (D2)
//   s1: 0 -> yv (x[h%4]), 1 -> 4-(h%4) (D3), 2 -> (h%4)+1 (D4)
constexpr int K_dh[9] = {0, 0, 0, -1, 1, -1, -1, 1, 1};
constexpr int K_dw[9] = {0, -1, 1, 0, 0, -1, 1, -1, 1};
constexpr int K_s0[9] = {0, 1, 2, 0, 0, 1, 2, 0, 0};
constexpr int K_s1[9] = {0, 0, 0, 1, 2, 0, 0, 1, 2};

__device__ __forceinline__ int pack2h(float a, float b) {
    union { _Float16 h[2]; int i; } u;
    u.h[0] = (_Float16)a;   // RNE, same as old scalar casts
    u.h[1] = (_Float16)b;
    return u.i;
}

// xor-16 then xor-32 butterfly sum on the VALU pipe via gfx950
// v_permlane16_swap_b32 / v_permlane32_swap_b32 (no DS ops, no latency hop).
// Pairing identical to the old ds_swizzle(x16)+shfl_xor(32) tree -> sums are
// bit-identical. Result replicated in all 64 lanes.
__device__ __forceinline__ float xsum64(float part) {
    float a = part, b = part;
    asm("v_permlane16_swap_b32 %0, %1" : "+v"(a), "+v"(b));   // rows: a=[r0,r0,r2,r2] b=[r1,r1,r3,r3]
    float s2 = a + b;                                          // part + part^16
    a = s2; b = s2;
    asm("v_permlane32_swap_b32 %0, %1" : "+v"(a), "+v"(b));   // a=[lo,lo] b=[hi,hi]
    return a + b;                                              // + ^32
}

// Pre-pass: ALr[(b*CH+cy)*CW+cx][o] = sum_c w0[o*66+c] * lr[b][c][cy][cx]  (fp32)
__global__ __launch_bounds__(256) void alr_prepass(const float* __restrict__ lr,
                                                   const float* __restrict__ w0,
                                                   float* __restrict__ alr) {
    const int idx = blockIdx.x * 256 + threadIdx.x;
    if (idx >= BB * CH * CW) return;
    const int b = idx / (CH * CW);
    const int cell = idx - b * (CH * CW);
    const float* lp = lr + (size_t)b * CC * CH * CW + cell;
    float lv[32];
#pragma unroll
    for (int c = 0; c < 32; c++) lv[c] = lp[(size_t)c * (CH * CW)];
    float acc[32];
#pragma unroll
    for (int o = 0; o < 32; o++) {
        float a = 0.f;
#pragma unroll
        for (int c = 0; c < 32; c++) a = fmaf(lv[c], w0[o * 66 + c], a);
        acc[o] = a;
    }
    float4* op = (float4*)(alr + (size_t)idx * 32);
#pragma unroll
    for (int j = 0; j < 8; j++)
        op[j] = make_float4(acc[4 * j], acc[4 * j + 1], acc[4 * j + 2], acc[4 * j + 3]);
}

// MFMA main, R7: QUAD-TILE ILP.
// R6 post-mortem: dual-tile cut 51->41.5us but VALUBusy stuck ~51% — each
// chain still stalls ~80% of its cycles on DS/MFMA latency, and residency is
// empirically pinned at ~2.5 blocks/CU across every config (R0-R6). So:
// more chains per wave. One wave owns 64 px = 4 independent 16-px tiles;
// per-d state (dd, row bound, ds offset) amortizes over 4 chains.
// Layer-4 reduce: v_permlane16/32_swap (VALU) replaces ds_swizzle+shfl (DS),
// bit-identical pairing, removes 4 DS ops per (d,tile).
// __launch_bounds__(256,3): VGPR cap ~170 for ~130 needed — NO spill possible
// (R3 lesson), and 3 blocks/CU >= observed residency, so nothing lost.
// Spill tripwire for post-mortem: WRITE_SIZE must stay ~9.2MB.
template <bool USE_WS>
__global__ __launch_bounds__(256, 3) void ercm_mfma(const float* __restrict__ hr,
                                                    const float* __restrict__ lr,
                                                    const float* __restrict__ alr,
                                                    const float* __restrict__ w0,
                                                    const float* __restrict__ w1,
                                                    const float* __restrict__ w2,
                                                    const float* __restrict__ w3,
                                                    float* __restrict__ out) {
    __shared__ _Float16 s_alr[54 * 40];     // [cell][o], 3 x 18 halo of coarse cells
    __shared__ _Float16 s_ahr[4][64 * 40];  // per wave: [px 0..63][o]

    const int tid = threadIdx.x;
    const int lane = tid & 63;
    const int ty = tid >> 6;       // wave id = h-row within block
    const int m16 = lane & 15;
    const int q = lane >> 4;       // quad
    const int bx = blockIdx.x;     // 0..7
    const int by = blockIdx.y;     // 0..63
    const int b = blockIdx.z;      // 0..1
    const int h = by * 4 + ty;
    const int wp0 = bx * 64;
    const size_t HW = (size_t)HH * WW;

    // ---- stage ALr halo tile (3 x 18 coarse cells), f16 ----
    const int cy0 = by, cx0 = bx * 16;
    if (USE_WS) {
        for (int i = tid; i < 54 * 32; i += 256) {
            const int c = i & 31, cell = i >> 5;
            const int row = cell / 18, col = cell - row * 18;
            const int gcy = cy0 - 1 + row, gcx = cx0 - 1 + col;
            float v = 0.f;
            if ((unsigned)gcy < (unsigned)CH && (unsigned)gcx < (unsigned)CW)
                v = alr[(((size_t)b * CH + gcy) * CW + gcx) * 32 + c];
            s_alr[cell * 40 + c] = (_Float16)v;
        }
    } else {
        for (int i = tid; i < 54 * 32; i += 256) {
            const int o = i & 31, cell = i >> 5;
            const int row = cell / 18, col = cell - row * 18;
            const int gcy = cy0 - 1 + row, gcx = cx0 - 1 + col;
            float a = 0.f;
            if ((unsigned)gcy < (unsigned)CH && (unsigned)gcx < (unsigned)CW) {
                const float* lp = lr + (size_t)b * CC * CH * CW + (size_t)gcy * CW + gcx;
#pragma unroll
                for (int c = 0; c < 32; c++) a = fmaf(lp[(size_t)c * (CH * CW)], w0[o * 66 + c], a);
            }
            s_alr[cell * 40 + o] = (_Float16)a;
        }
    }

    // ---- load weight fragments (once). Same lane layout serves A or B. ----
    f16x8 w1B, w0hB0, w0hB1, w2B;
    {
        const float* p1 = w1 + m16 * 32 + q * 8;
        const float* p00 = w0 + m16 * 66 + 32 + q * 8;
        const float* p01 = w0 + (m16 + 16) * 66 + 32 + q * 8;
        const bool w2ok = (m16 < 8) && (q < 2);
#pragma unroll
        for (int j = 0; j < 8; j++) {
            w1B[j] = (_Float16)p1[j];
            w0hB0[j] = (_Float16)p00[j];
            w0hB1[j] = (_Float16)p01[j];
            w2B[j] = (_Float16)(w2ok ? w2[m16 * 16 + q * 8 + j] : 0.f);
        }
    }
    // layer-1 distance weights for this lane's channels o=q*8+j, as f32x2 pairs
    f32x2 w0d0v[4], w0d1v[4];
#pragma unroll
    for (int jp = 0; jp < 4; jp++) {
        w0d0v[jp] = f32x2{w0[(q * 8 + 2 * jp) * 66 + 64], w0[(q * 8 + 2 * jp + 1) * 66 + 64]};
        w0d1v[jp] = f32x2{w0[(q * 8 + 2 * jp) * 66 + 65], w0[(q * 8 + 2 * jp + 1) * 66 + 65]};
    }
    // layer-4 weights per D3 row ch3 = q*4+r (rows >=8 are exact zeros)
    float w3c[4];
#pragma unroll
    for (int r = 0; r < 4; r++) w3c[r] = (q < 2) ? w3[q * 4 + r] : 0.f;

    // per-lane distance operand values (pixel phase xm = w%4; ym wave-uniform)
    const int xm = m16 & 3;
    const float xv = (float)(xm < 2 ? xm - 2 : xm - 1);
    const float x1 = (float)(4 - xm), x2 = (float)(xm + 1);
    const int ym = h & 3;
    const float yv = (float)(ym < 2 ? ym - 2 : ym - 1);
    const float y1 = (float)(4 - ym), y2 = (float)(ym + 1);

    // bpermute byte-addresses for the layer2->3 q-exchange (target q pulls
    // D2 rows from holder lanes m16+32q, m16+32q+16; q>=2 wraps -> garbage
    // that is multiplied by w2's zero K-rows, so it never contributes).
    const int A0 = ((m16 + 32 * q) & 63) << 2;
    const int A1 = ((m16 + 32 * q + 16) & 63) << 2;

    _Float16* sa = s_ahr[ty];

    __syncthreads();  // s_alr staged (everything else is per-wave)

    const float* hp = hr + (size_t)b * CC * HW + (size_t)h * WW + wp0;

    // ---- Phase A, 4 tiles: ahr = hr . w0hr via 8 MFMAs, D[px][ch] -> sa ----
#pragma unroll
    for (int T = 0; T < 4; T++) {
        f16x8 a;
#pragma unroll
        for (int j = 0; j < 8; j++)
            a[j] = (_Float16)hp[(size_t)(q * 8 + j) * HW + T * 16 + m16];
        f32x4 p0 = {0.f, 0.f, 0.f, 0.f}, p1 = {0.f, 0.f, 0.f, 0.f};
        p0 = __builtin_amdgcn_mfma_f32_16x16x32_f16(a, w0hB0, p0, 0, 0, 0);
        p1 = __builtin_amdgcn_mfma_f32_16x16x32_f16(a, w0hB1, p1, 0, 0, 0);
#pragma unroll
        for (int r = 0; r < 4; r++) {
            const int row = T * 16 + q * 4 + r;
            sa[row * 40 + m16] = (_Float16)p0[r];        // ch 0..15
            sa[row * 40 + 16 + m16] = (_Float16)p1[r];   // ch 16..31
        }
    }
    // hoist ahr to f32 registers ONCE per tile (reused by all 9 directions)
    f32x2 ah[4][4];
#pragma unroll
    for (int T = 0; T < 4; T++) {
        const f16x8 ahv = *(const f16x8*)&sa[(T * 16 + m16) * 40 + q * 8];
#pragma unroll
        for (int jp = 0; jp < 4; jp++)
            ah[T][jp] = f32x2{(float)ahv[2 * jp], (float)ahv[2 * jp + 1]};
    }

    float l[4][9];
#pragma unroll
    for (int d = 0; d < 9; d++) {
        const int dh = K_dh[d], dw = K_dw[d];
        const float d0 = (K_s0[d] == 0) ? xv : ((K_s0[d] == 1) ? x1 : x2);
        const float d1 = (K_s1[d] == 0) ? yv : ((K_s1[d] == 1) ? y1 : y2);
        const f32x2 d0v = {d0, d0}, d1v = {d1, d1};
        const int off = ((1 + dh) * 18 + (1 + dw)) * 40;   // compile-time
        const bool okh = (unsigned)(h + 4 * dh) < (unsigned)HH;

        // shared per-d distance contribution (tile-invariant)
        f32x2 dd[4];
#pragma unroll
        for (int jp = 0; jp < 4; jp++)
            dd[jp] = __builtin_elementwise_fma(w0d0v[jp], d0v, w0d1v[jp] * d1v);

#pragma unroll
        for (int T = 0; T < 4; T++) {
            // layer 1: A1[k=ch1][n=px] = leaky(ahr + alr + dd)
            const f16x8 alv =
                *(const f16x8*)&s_alr[(T * 4 + (m16 >> 2)) * 40 + q * 8 + off];
            f16x8 a1;
#pragma unroll
            for (int jp = 0; jp < 4; jp++) {
                f32x2 v = ah[T][jp] + f32x2{(float)alv[2 * jp], (float)alv[2 * jp + 1]};
                v = v + dd[jp];
                v = __builtin_elementwise_max(v, v * 0.01f);
                a1[2 * jp] = (_Float16)v[0];
                a1[2 * jp + 1] = (_Float16)v[1];
            }
            // layer 2 SWAPPED: D2[ch2][px] (lane: rows ch2=q*4+r, col px=m16)
            f32x4 c2 = {0.f, 0.f, 0.f, 0.f};
            c2 = __builtin_amdgcn_mfma_f32_16x16x32_f16(w1B, a1, c2, 0, 0, 0);

            // layer2->3 glue: leaky, pack rows to f16 pairs, q-exchange via
            // 4 bpermutes -> B3-frag a3[k=ch2=q*8+j][n=px=m16]
            f16x8 a3;
            {
                float e0 = fmaxf(c2[0], 0.01f * c2[0]), e1 = fmaxf(c2[1], 0.01f * c2[1]);
                float e2 = fmaxf(c2[2], 0.01f * c2[2]), e3 = fmaxf(c2[3], 0.01f * c2[3]);
                const int pk0 = pack2h(e0, e1), pk1 = pack2h(e2, e3);
                union { int i[4]; f16x8 v; } u;
                u.i[0] = __builtin_amdgcn_ds_bpermute(A0, pk0);
                u.i[1] = __builtin_amdgcn_ds_bpermute(A0, pk1);
                u.i[2] = __builtin_amdgcn_ds_bpermute(A1, pk0);
                u.i[3] = __builtin_amdgcn_ds_bpermute(A1, pk1);
                a3 = u.v;
            }
            // layer 3 SWAPPED: D3[ch3][px]; rows ch3>=8 exact 0 (w2 A-rows zero)
            f32x4 c3 = {0.f, 0.f, 0.f, 0.f};
            c3 = __builtin_amdgcn_mfma_f32_16x16x32_f16(w2B, a3, c3, 0, 0, 0);

            // layer 4: in-lane fma over ch3=q*4+r, then xor16+xor32 VALU
            // butterfly (bit-identical to old swz+shfl tree).
            float part = 0.f;
#pragma unroll
            for (int r = 0; r < 4; r++) {
                const float lv = fmaxf(c3[r], 0.01f * c3[r]);
                part = fmaf(w3c[r], lv, part);
            }
            const float lg = xsum64(part);
            const int wn = wp0 + T * 16 + m16;   // this lane's pixel, tile T
            const bool ok = okh && ((unsigned)(wn + 4 * dw) < (unsigned)WW);
            l[T][d] = ok ? lg : -100.0f;
        }
    }

    // softmax per tile (replicated across q; lane owns px=m16); writers lane<16
#pragma unroll
    for (int T = 0; T < 4; T++) {
        float mx = l[T][0];
#pragma unroll
        for (int d = 1; d < 9; d++) mx = fmaxf(mx, l[T][d]);
        float s = 0.f;
#pragma unroll
        for (int d = 0; d < 9; d++) {
            l[T][d] = __expf(l[T][d] - mx);
            s += l[T][d];
        }
        const float inv = __builtin_amdgcn_rcpf(s);
        if (lane < 16) {
            float* op = out + (size_t)b * 9 * HW + (size_t)h * WW + (wp0 + T * 16 + m16);
#pragma unroll
            for (int d = 0; d < 9; d++) op[(size_t)d * HW] = l[T][d] * inv;
        }
    }
}

extern "C" void kernel_launch(void* const* d_in, const int* in_sizes, int n_in,
                              void* d_out, int out_size, void* d_ws, size_t ws_size,
                              hipStream_t stream) {
    const float* lr = (const float*)d_in[0];
    const float* hr = (const float*)d_in[1];
    // d_in[2], d_in[3] (lr_feature_r / hr_feature_r) are unused by the reference.
    const float* w0 = (const float*)d_in[4];
    const float* w1 = (const float*)d_in[5];
    const float* w2 = (const float*)d_in[6];
    const float* w3 = (const float*)d_in[7];
    float* out = (float*)d_out;

    const size_t alr_bytes = (size_t)BB * CH * CW * 32 * sizeof(float);  // 2 MB
    dim3 grid(WW / 64, HH / 4, BB);  // 1024 blocks of 256 thr (4 waves), 64 px/wave

    if (ws_size >= alr_bytes) {
        float* alr = (float*)d_ws;
        alr_prepass<<<(BB * CH * CW + 255) / 256, 256, 0, stream>>>(lr, w0, alr);
        ercm_mfma<true><<<grid, 256, 0, stream>>>(hr, lr, alr, w0, w1, w2, w3, out);
    } else {
        ercm_mfma<false><<<grid, 256, 0, stream>>>(hr, lr, nullptr, w0, w1, w2, w3, out);
    }
}

// Round 9
// 141.920 us; speedup vs baseline: 1.0814x; 1.0814x over previous
//
#include <hip/hip_runtime.h>
#include <math.h>

#define SC 4
#define BB 2
#define CC 32
#define HH 256
#define WW 512
#define CH (HH / SC)   // 64
#define CW (WW / SC)   // 128

using f16x8 = __attribute__((ext_vector_type(8))) _Float16;
using f16x4 = __attribute__((ext_vector_type(4))) _Float16;
using f32x4 = __attribute__((ext_vector_type(4))) float;
using f32x2 = __attribute__((ext_vector_type(2))) float;

// Direction metadata (output channel order: c, l, r, t, b, lt, rt, lb, rb)
//   s0: 0 -> xv (x[w%4]), 1 -> 4-(w%4) (D1), 2 -> (w%4)+1 (D2)
//   s1: 0 -> yv (x[h%4]), 1 -> 4-(h%4) (D3), 2 -> (h%4)+1 (D4)
constexpr int K_dh[9] = {0, 0, 0, -1, 1, -1, -1, 1, 1};
constexpr int K_dw[9] = {0, -1, 1, 0, 0, -1, 1, -1, 1};
constexpr int K_s0[9] = {0, 1, 2, 0, 0, 1, 2, 0, 0};
constexpr int K_s1[9] = {0, 0, 0, 1, 2, 0, 0, 1, 2};

__device__ __forceinline__ float swz_x16(float v) {
    // lane ^ 16 within each 32-lane half: BitMode offset = (16<<10)|0x1F
    return __int_as_float(__builtin_amdgcn_ds_swizzle(__float_as_int(v), 0x401F));
}

// Pre-pass: ALr[(b*CH+cy)*CW+cx][o] = sum_c w0[o*66+c] * lr[b][c][cy][cx]  (fp32)
__global__ __launch_bounds__(256) void alr_prepass(const float* __restrict__ lr,
                                                   const float* __restrict__ w0,
                                                   float* __restrict__ alr) {
    const int idx = blockIdx.x * 256 + threadIdx.x;
    if (idx >= BB * CH * CW) return;
    const int b = idx / (CH * CW);
    const int cell = idx - b * (CH * CW);
    const float* lp = lr + (size_t)b * CC * CH * CW + cell;
    float lv[32];
#pragma unroll
    for (int c = 0; c < 32; c++) lv[c] = lp[(size_t)c * (CH * CW)];
    float acc[32];
#pragma unroll
    for (int o = 0; o < 32; o++) {
        float a = 0.f;
#pragma unroll
        for (int c = 0; c < 32; c++) a = fmaf(lv[c], w0[o * 66 + c], a);
        acc[o] = a;
    }
    float4* op = (float4*)(alr + (size_t)idx * 32);
#pragma unroll
    for (int j = 0; j < 8; j++)
        op[j] = make_float4(acc[4 * j], acc[4 * j + 1], acc[4 * j + 2], acc[4 * j + 3]);
}

// MFMA main, R9 = R8 with the intrinsic name fixed (16x16x16f16 — the legacy
// K=16 builtin has NO underscore before f16; only gfx950-new 2xK shapes do).
// R8 theory (untested due to compile error): R6's critical path
// MFMA2 -> leaky/pack -> 4x ds_bpermute -> MFMA3 existed only because
// layer-3 consumed a 16x16x32 B-frag (k=q*8+j). v_mfma_f32_16x16x16_f16's
// fragment layout is k=q*4+j — exactly where D2[ch2=q*4+r][px=m16] already
// sits, and layer-3's K IS 16. So: b3 = in-lane pack of leaky(c2) (f16x4),
// w2 held as the 16x16x16 A-frag w2A[m=ch3=m16][k=q*4+j] (rows>=8 zero ->
// D3 rows 8..15 exact 0, masked by w3c as before). Deletes 8 bpermutes +
// addr setup per d; the MFMA2->MFMA3 segment becomes pure VALU.
//  (layers 1/2 unchanged: A1[k=ch1][px] -> mfma(w1B, a1) -> D2[ch2][px];
//   layer 4 unchanged: in-lane fma + swz(x16)+shfl(x32) cross-lane sum.)
// Geometry: R6's dual-tile (2048 blocks, 256 thr, 4 waves, 32 px/wave) —
// R7 showed quad-tile regresses (rematerialization at VGPR 72, SGPR 112).
// __launch_bounds__(256,4) = 128-VGPR cap (R3 lesson: never force 8/EU).
template <bool USE_WS>
__global__ __launch_bounds__(256, 4) void ercm_mfma(const float* __restrict__ hr,
                                                    const float* __restrict__ lr,
                                                    const float* __restrict__ alr,
                                                    const float* __restrict__ w0,
                                                    const float* __restrict__ w1,
                                                    const float* __restrict__ w2,
                                                    const float* __restrict__ w3,
                                                    float* __restrict__ out) {
    __shared__ _Float16 s_alr[30 * 40];     // [cell][o], 3 x 10 halo of coarse cells
    __shared__ _Float16 s_ahr[4][32 * 40];  // per wave: [px 0..31][o] (both tiles)

    const int tid = threadIdx.x;
    const int lane = tid & 63;
    const int ty = tid >> 6;       // wave id = h-row within block
    const int m16 = lane & 15;
    const int q = lane >> 4;       // quad
    const int bx = blockIdx.x;     // 0..15
    const int by = blockIdx.y;     // 0..63
    const int b = blockIdx.z;      // 0..1
    const int h = by * 4 + ty;
    const int wp0 = bx * 32;
    const size_t HW = (size_t)HH * WW;

    // ---- stage ALr halo tile (3 x 10 coarse cells), f16 ----
    const int cy0 = by, cx0 = bx * 8;
    if (USE_WS) {
        for (int i = tid; i < 30 * 32; i += 256) {
            const int c = i & 31, cell = i >> 5;
            const int row = cell / 10, col = cell - row * 10;
            const int gcy = cy0 - 1 + row, gcx = cx0 - 1 + col;
            float v = 0.f;
            if ((unsigned)gcy < (unsigned)CH && (unsigned)gcx < (unsigned)CW)
                v = alr[(((size_t)b * CH + gcy) * CW + gcx) * 32 + c];
            s_alr[cell * 40 + c] = (_Float16)v;
        }
    } else {
        for (int i = tid; i < 30 * 32; i += 256) {
            const int o = i & 31, cell = i >> 5;
            const int row = cell / 10, col = cell - row * 10;
            const int gcy = cy0 - 1 + row, gcx = cx0 - 1 + col;
            float a = 0.f;
            if ((unsigned)gcy < (unsigned)CH && (unsigned)gcx < (unsigned)CW) {
                const float* lp = lr + (size_t)b * CC * CH * CW + (size_t)gcy * CW + gcx;
#pragma unroll
                for (int c = 0; c < 32; c++) a = fmaf(lp[(size_t)c * (CH * CW)], w0[o * 66 + c], a);
            }
            s_alr[cell * 40 + o] = (_Float16)a;
        }
    }

    // ---- load weight fragments (once). Same lane layout serves A or B. ----
    f16x8 w1B, w0hB0, w0hB1;
    f16x4 w2A;  // 16x16x16 A-frag: [m=ch3=m16][k=ch2=q*4+j], rows>=8 zero
    {
        const float* p1 = w1 + m16 * 32 + q * 8;
        const float* p00 = w0 + m16 * 66 + 32 + q * 8;
        const float* p01 = w0 + (m16 + 16) * 66 + 32 + q * 8;
#pragma unroll
        for (int j = 0; j < 8; j++) {
            w1B[j] = (_Float16)p1[j];
            w0hB0[j] = (_Float16)p00[j];
            w0hB1[j] = (_Float16)p01[j];
        }
        const bool w2ok = (m16 < 8);
#pragma unroll
        for (int j = 0; j < 4; j++)
            w2A[j] = (_Float16)(w2ok ? w2[m16 * 16 + q * 4 + j] : 0.f);
    }
    // layer-1 distance weights for this lane's channels o=q*8+j, as f32x2 pairs
    f32x2 w0d0v[4], w0d1v[4];
#pragma unroll
    for (int jp = 0; jp < 4; jp++) {
        w0d0v[jp] = f32x2{w0[(q * 8 + 2 * jp) * 66 + 64], w0[(q * 8 + 2 * jp + 1) * 66 + 64]};
        w0d1v[jp] = f32x2{w0[(q * 8 + 2 * jp) * 66 + 65], w0[(q * 8 + 2 * jp + 1) * 66 + 65]};
    }
    // layer-4 weights per D3 row ch3 = q*4+r (rows >=8 are exact zeros)
    float w3c[4];
#pragma unroll
    for (int r = 0; r < 4; r++) w3c[r] = (q < 2) ? w3[q * 4 + r] : 0.f;

    // per-lane distance operand values (pixel phase xm = w%4; ym wave-uniform)
    const int xm = m16 & 3;
    const float xv = (float)(xm < 2 ? xm - 2 : xm - 1);
    const float x1 = (float)(4 - xm), x2 = (float)(xm + 1);
    const int ym = h & 3;
    const float yv = (float)(ym < 2 ? ym - 2 : ym - 1);
    const float y1 = (float)(4 - ym), y2 = (float)(ym + 1);

    _Float16* sa = s_ahr[ty];

    __syncthreads();  // s_alr staged (everything else is per-wave)

    const float* hp = hr + (size_t)b * CC * HW + (size_t)h * WW + wp0;

    // ---- Phase A, both tiles: ahr = hr . w0hr via 4 MFMAs (D[px][ch]) ----
    f16x8 aT0, aT1;
#pragma unroll
    for (int j = 0; j < 8; j++) {
        aT0[j] = (_Float16)hp[(size_t)(q * 8 + j) * HW + m16];
        aT1[j] = (_Float16)hp[(size_t)(q * 8 + j) * HW + 16 + m16];
    }
    {
        f32x4 p00 = {0.f, 0.f, 0.f, 0.f}, p01 = {0.f, 0.f, 0.f, 0.f};
        f32x4 p10 = {0.f, 0.f, 0.f, 0.f}, p11 = {0.f, 0.f, 0.f, 0.f};
        p00 = __builtin_amdgcn_mfma_f32_16x16x32_f16(aT0, w0hB0, p00, 0, 0, 0);
        p01 = __builtin_amdgcn_mfma_f32_16x16x32_f16(aT0, w0hB1, p01, 0, 0, 0);
        p10 = __builtin_amdgcn_mfma_f32_16x16x32_f16(aT1, w0hB0, p10, 0, 0, 0);
        p11 = __builtin_amdgcn_mfma_f32_16x16x32_f16(aT1, w0hB1, p11, 0, 0, 0);
#pragma unroll
        for (int r = 0; r < 4; r++) {
            const int row = q * 4 + r;
            sa[row * 40 + m16] = (_Float16)p00[r];
            sa[row * 40 + 16 + m16] = (_Float16)p01[r];
            sa[(16 + row) * 40 + m16] = (_Float16)p10[r];
            sa[(16 + row) * 40 + 16 + m16] = (_Float16)p11[r];
        }
    }
    // hoist ahr to f32 registers ONCE per tile (reused by all 9 directions)
    const f16x8 ahv0 = *(const f16x8*)&sa[m16 * 40 + q * 8];
    const f16x8 ahv1 = *(const f16x8*)&sa[(16 + m16) * 40 + q * 8];
    f32x2 ah0[4], ah1[4];
#pragma unroll
    for (int jp = 0; jp < 4; jp++) {
        ah0[jp] = f32x2{(float)ahv0[2 * jp], (float)ahv0[2 * jp + 1]};
        ah1[jp] = f32x2{(float)ahv1[2 * jp], (float)ahv1[2 * jp + 1]};
    }

    // alr halo bases per tile; per-d cell adds a compile-time offset
    // ((1+dh)*10 + (1+dw)) * 40 halfs.
    const _Float16* alp0 = &s_alr[(m16 >> 2) * 40 + q * 8];
    const _Float16* alp1 = &s_alr[(4 + (m16 >> 2)) * 40 + q * 8];
    const int wown0 = wp0 + m16;        // this lane's pixel, tile 0 (q-uniform)
    const int wown1 = wp0 + 16 + m16;   // tile 1

    float l0[9], l1[9];
#pragma unroll
    for (int d = 0; d < 9; d++) {
        const int dh = K_dh[d], dw = K_dw[d];
        const float d0 = (K_s0[d] == 0) ? xv : ((K_s0[d] == 1) ? x1 : x2);
        const float d1 = (K_s1[d] == 0) ? yv : ((K_s1[d] == 1) ? y1 : y2);
        const f32x2 d0v = {d0, d0}, d1v = {d1, d1};
        const int off = ((1 + dh) * 10 + (1 + dw)) * 40;

        // shared per-d distance contribution (t-invariant)
        f32x2 dd[4];
#pragma unroll
        for (int jp = 0; jp < 4; jp++)
            dd[jp] = __builtin_elementwise_fma(w0d0v[jp], d0v, w0d1v[jp] * d1v);

        // layer 1 (both tiles): A1[k=ch1][n=px] = leaky(ahr + alr + dd)
        const f16x8 alv0 = *(const f16x8*)(alp0 + off);
        const f16x8 alv1 = *(const f16x8*)(alp1 + off);
        f16x8 a1_0, a1_1;
#pragma unroll
        for (int jp = 0; jp < 4; jp++) {
            f32x2 v0 = ah0[jp] + f32x2{(float)alv0[2 * jp], (float)alv0[2 * jp + 1]};
            f32x2 v1 = ah1[jp] + f32x2{(float)alv1[2 * jp], (float)alv1[2 * jp + 1]};
            v0 = v0 + dd[jp];
            v1 = v1 + dd[jp];
            v0 = __builtin_elementwise_max(v0, v0 * 0.01f);
            v1 = __builtin_elementwise_max(v1, v1 * 0.01f);
            a1_0[2 * jp] = (_Float16)v0[0];
            a1_0[2 * jp + 1] = (_Float16)v0[1];
            a1_1[2 * jp] = (_Float16)v1[0];
            a1_1[2 * jp + 1] = (_Float16)v1[1];
        }
        // layer 2 SWAPPED: D2[ch2][px] (lane: rows ch2=q*4+r, col px=m16)
        f32x4 c2_0 = {0.f, 0.f, 0.f, 0.f}, c2_1 = {0.f, 0.f, 0.f, 0.f};
        c2_0 = __builtin_amdgcn_mfma_f32_16x16x32_f16(w1B, a1_0, c2_0, 0, 0, 0);
        c2_1 = __builtin_amdgcn_mfma_f32_16x16x32_f16(w1B, a1_1, c2_1, 0, 0, 0);

        // layer2->3 glue: pure in-lane now. D2 rows ch2=q*4+r ARE the
        // 16x16x16 B-frag k-rows (k=q*4+r) -> b3 = pack(leaky(c2)).
        f16x4 b3_0, b3_1;
#pragma unroll
        for (int r = 0; r < 4; r++) {
            const float e0 = fmaxf(c2_0[r], 0.01f * c2_0[r]);
            const float e1 = fmaxf(c2_1[r], 0.01f * c2_1[r]);
            b3_0[r] = (_Float16)e0;
            b3_1[r] = (_Float16)e1;
        }
        // layer 3 (16x16x16, K=ch2=16 exact): D3[ch3=q*4+r][px=m16];
        // rows ch3>=8 exact 0 (w2A rows zero)
        f32x4 c3_0 = {0.f, 0.f, 0.f, 0.f}, c3_1 = {0.f, 0.f, 0.f, 0.f};
        c3_0 = __builtin_amdgcn_mfma_f32_16x16x16f16(w2A, b3_0, c3_0, 0, 0, 0);
        c3_1 = __builtin_amdgcn_mfma_f32_16x16x16f16(w2A, b3_1, c3_1, 0, 0, 0);

        // layer 4: in-lane fma over ch3=q*4+r, then sum the 4 q-partials
        // (lanes m16+16q) with swz(x16) + shfl(x32). Logit replicated in all
        // 64 lanes for px=m16.
        {
            float part = 0.f;
#pragma unroll
            for (int r = 0; r < 4; r++) {
                const float lv = fmaxf(c3_0[r], 0.01f * c3_0[r]);
                part = fmaf(w3c[r], lv, part);
            }
            float s2 = part + swz_x16(part);
            const float lg = s2 + __shfl_xor(s2, 32, 64);
            const bool ok = ((unsigned)(h + 4 * dh) < (unsigned)HH) &&
                            ((unsigned)(wown0 + 4 * dw) < (unsigned)WW);
            l0[d] = ok ? lg : -100.0f;
        }
        {
            float part = 0.f;
#pragma unroll
            for (int r = 0; r < 4; r++) {
                const float lv = fmaxf(c3_1[r], 0.01f * c3_1[r]);
                part = fmaf(w3c[r], lv, part);
            }
            float s2 = part + swz_x16(part);
            const float lg = s2 + __shfl_xor(s2, 32, 64);
            const bool ok = ((unsigned)(h + 4 * dh) < (unsigned)HH) &&
                            ((unsigned)(wown1 + 4 * dw) < (unsigned)WW);
            l1[d] = ok ? lg : -100.0f;
        }
    }

    // softmax per tile (replicated across q; lane owns px=m16); writers q==0
    {
        float mx = l0[0];
#pragma unroll
        for (int d = 1; d < 9; d++) mx = fmaxf(mx, l0[d]);
        float s = 0.f;
#pragma unroll
        for (int d = 0; d < 9; d++) {
            l0[d] = __expf(l0[d] - mx);
            s += l0[d];
        }
        const float inv = __builtin_amdgcn_rcpf(s);
        if (lane < 16) {
            float* op = out + (size_t)b * 9 * HW + (size_t)h * WW + wown0;
#pragma unroll
            for (int d = 0; d < 9; d++) op[(size_t)d * HW] = l0[d] * inv;
        }
    }
    {
        float mx = l1[0];
#pragma unroll
        for (int d = 1; d < 9; d++) mx = fmaxf(mx, l1[d]);
        float s = 0.f;
#pragma unroll
        for (int d = 0; d < 9; d++) {
            l1[d] = __expf(l1[d] - mx);
            s += l1[d];
        }
        const float inv = __builtin_amdgcn_rcpf(s);
        if (lane < 16) {
            float* op = out + (size_t)b * 9 * HW + (size_t)h * WW + wown1;
#pragma unroll
            for (int d = 0; d < 9; d++) op[(size_t)d * HW] = l1[d] * inv;
        }
    }
}

extern "C" void kernel_launch(void* const* d_in, const int* in_sizes, int n_in,
                              void* d_out, int out_size, void* d_ws, size_t ws_size,
                              hipStream_t stream) {
    const float* lr = (const float*)d_in[0];
    const float* hr = (const float*)d_in[1];
    // d_in[2], d_in[3] (lr_feature_r / hr_feature_r) are unused by the reference.
    const float* w0 = (const float*)d_in[4];
    const float* w1 = (const float*)d_in[5];
    const float* w2 = (const float*)d_in[6];
    const float* w3 = (const float*)d_in[7];
    float* out = (float*)d_out;

    const size_t alr_bytes = (size_t)BB * CH * CW * 32 * sizeof(float);  // 2 MB
    dim3 grid(WW / 32, HH / 4, BB);  // 2048 blocks of 256 thr (4 waves)

    if (ws_size >= alr_bytes) {
        float* alr = (float*)d_ws;
        alr_prepass<<<(BB * CH * CW + 255) / 256, 256, 0, stream>>>(lr, w0, alr);
        ercm_mfma<true><<<grid, 256, 0, stream>>>(hr, lr, alr, w0, w1, w2, w3, out);
    } else {
        ercm_mfma<false><<<grid, 256, 0, stream>>>(hr, lr, nullptr, w0, w1, w2, w3, out);
    }
}

// Round 12
// 141.048 us; speedup vs baseline: 1.0881x; 1.0062x over previous
//
#include <hip/hip_runtime.h>
#include <math.h>

#define SC 4
#define BB 2
#define CC 32
#define HH 256
#define WW 512
#define CH (HH / SC)   // 64
#define CW (WW / SC)   // 128

using f16x8 = __attribute__((ext_vector_type(8))) _Float16;
using f16x4 = __attribute__((ext_vector_type(4))) _Float16;
using f32x4 = __attribute__((ext_vector_type(4))) float;
using f32x2 = __attribute__((ext_vector_type(2))) float;

// Direction metadata (output channel order: c, l, r, t, b, lt, rt, lb, rb)
//   s0: 0 -> xv (x[w%4]), 1 -> 4-(w%4) (D1), 2 -> (w%4)+1 (D2)
//   s1: 0 -> yv (x[h%4]), 1 -> 4-(h%4) (D3), 2 -> (h%4)+1 (D4)
constexpr int K_dh[9] = {0, 0, 0, -1, 1, -1, -1, 1, 1};
constexpr int K_dw[9] = {0, -1, 1, 0, 0, -1, 1, -1, 1};
constexpr int K_s0[9] = {0, 1, 2, 0, 0, 1, 2, 0, 0};
constexpr int K_s1[9] = {0, 0, 0, 1, 2, 0, 0, 1, 2};

__device__ __forceinline__ float swz_x16(float v) {
    // lane ^ 16 within each 32-lane half: BitMode offset = (16<<10)|0x1F
    return __int_as_float(__builtin_amdgcn_ds_swizzle(__float_as_int(v), 0x401F));
}

// LESSON (R10/R11 post-mortem): the permlane-swap inline asm
//   asm("v_permlane16_swap_b32 %0, %1" : "+v"(a), "+v"(b))
// with a==b on input can be register-COALESCED by the allocator into
// v_permlane16_swap v0, v0 (self-swap -> 2*permuted, not the butterfly sum).
// It passed in R7 and silently broke in R10/R11 (absmax 1.0, raw 468) purely
// from allocation context. Do not reintroduce without forcing distinct
// registers. The DS-based reduce below (swz_x16 + __shfl_xor) is the
// R9-proven path.

// Pre-pass: ALr[(b*CH+cy)*CW+cx][o] = sum_c w0[o*66+c] * lr[b][c][cy][cx]  (fp32)
__global__ __launch_bounds__(256) void alr_prepass(const float* __restrict__ lr,
                                                   const float* __restrict__ w0,
                                                   float* __restrict__ alr) {
    const int idx = blockIdx.x * 256 + threadIdx.x;
    if (idx >= BB * CH * CW) return;
    const int b = idx / (CH * CW);
    const int cell = idx - b * (CH * CW);
    const float* lp = lr + (size_t)b * CC * CH * CW + cell;
    float lv[32];
#pragma unroll
    for (int c = 0; c < 32; c++) lv[c] = lp[(size_t)c * (CH * CW)];
    float acc[32];
#pragma unroll
    for (int o = 0; o < 32; o++) {
        float a = 0.f;
#pragma unroll
        for (int c = 0; c < 32; c++) a = fmaf(lv[c], w0[o * 66 + c], a);
        acc[o] = a;
    }
    float4* op = (float4*)(alr + (size_t)idx * 32);
#pragma unroll
    for (int j = 0; j < 8; j++)
        op[j] = make_float4(acc[4 * j], acc[4 * j + 1], acc[4 * j + 2], acc[4 * j + 3]);
}

// MFMA main, R12 = R9 (last PASSING, main ~37us) + ONE bisected change:
//   f32 s_alr staging: per-(d,tile) alr read = 2x ds_read_b128 (f32),
//   deleting 8x v_cvt_f32_f16 per (d,tile) (288/wave) and removing alr's
//   f16 rounding (absmax can only shrink).
// Layer-4 reduce and tails are EXACTLY R9's (swz_x16 + shfl_xor, two
// lane<16 store blocks) — the xsum64 inline-asm path is withdrawn per the
// coalescing lesson above.
// Everything else identical to R9: dual-tile (2048 blocks, 256 thr, 4 waves,
// 32 px/wave), swapped layer-2 (D2[ch2][px]), in-lane K16 layer-3
// (v_mfma_f32_16x16x16f16, b3 = pack(leaky(c2)), w2A rows>=8 zero).
// R3 lesson: __launch_bounds__(256,4) (128-VGPR cap), never force 8/EU.
// R7 lesson: do not widen to quad-tile (rematerialization).
template <bool USE_WS>
__global__ __launch_bounds__(256, 4) void ercm_mfma(const float* __restrict__ hr,
                                                    const float* __restrict__ lr,
                                                    const float* __restrict__ alr,
                                                    const float* __restrict__ w0,
                                                    const float* __restrict__ w1,
                                                    const float* __restrict__ w2,
                                                    const float* __restrict__ w3,
                                                    float* __restrict__ out) {
    __shared__ float    s_alr[30 * 40];     // [cell][o] FP32, 3 x 10 halo, stride 40 (160B rows)
    __shared__ _Float16 s_ahr[4][32 * 40];  // per wave: [px 0..31][o] (both tiles)

    const int tid = threadIdx.x;
    const int lane = tid & 63;
    const int ty = tid >> 6;       // wave id = h-row within block
    const int m16 = lane & 15;
    const int q = lane >> 4;       // quad
    const int bx = blockIdx.x;     // 0..15
    const int by = blockIdx.y;     // 0..63
    const int b = blockIdx.z;      // 0..1
    const int h = by * 4 + ty;
    const int wp0 = bx * 32;
    const size_t HW = (size_t)HH * WW;

    // ---- stage ALr halo tile (3 x 10 coarse cells), FP32 ----
    const int cy0 = by, cx0 = bx * 8;
    if (USE_WS) {
        for (int i = tid; i < 30 * 32; i += 256) {
            const int c = i & 31, cell = i >> 5;
            const int row = cell / 10, col = cell - row * 10;
            const int gcy = cy0 - 1 + row, gcx = cx0 - 1 + col;
            float v = 0.f;
            if ((unsigned)gcy < (unsigned)CH && (unsigned)gcx < (unsigned)CW)
                v = alr[(((size_t)b * CH + gcy) * CW + gcx) * 32 + c];
            s_alr[cell * 40 + c] = v;
        }
    } else {
        for (int i = tid; i < 30 * 32; i += 256) {
            const int o = i & 31, cell = i >> 5;
            const int row = cell / 10, col = cell - row * 10;
            const int gcy = cy0 - 1 + row, gcx = cx0 - 1 + col;
            float a = 0.f;
            if ((unsigned)gcy < (unsigned)CH && (unsigned)gcx < (unsigned)CW) {
                const float* lp = lr + (size_t)b * CC * CH * CW + (size_t)gcy * CW + gcx;
#pragma unroll
                for (int c = 0; c < 32; c++) a = fmaf(lp[(size_t)c * (CH * CW)], w0[o * 66 + c], a);
            }
            s_alr[cell * 40 + o] = a;
        }
    }

    // ---- load weight fragments (once). Same lane layout serves A or B. ----
    f16x8 w1B, w0hB0, w0hB1;
    f16x4 w2A;  // 16x16x16 A-frag: [m=ch3=m16][k=ch2=q*4+j], rows>=8 zero
    {
        const float* p1 = w1 + m16 * 32 + q * 8;
        const float* p00 = w0 + m16 * 66 + 32 + q * 8;
        const float* p01 = w0 + (m16 + 16) * 66 + 32 + q * 8;
#pragma unroll
        for (int j = 0; j < 8; j++) {
            w1B[j] = (_Float16)p1[j];
            w0hB0[j] = (_Float16)p00[j];
            w0hB1[j] = (_Float16)p01[j];
        }
        const bool w2ok = (m16 < 8);
#pragma unroll
        for (int j = 0; j < 4; j++)
            w2A[j] = (_Float16)(w2ok ? w2[m16 * 16 + q * 4 + j] : 0.f);
    }
    // layer-1 distance weights for this lane's channels o=q*8+j, as f32x2 pairs
    f32x2 w0d0v[4], w0d1v[4];
#pragma unroll
    for (int jp = 0; jp < 4; jp++) {
        w0d0v[jp] = f32x2{w0[(q * 8 + 2 * jp) * 66 + 64], w0[(q * 8 + 2 * jp + 1) * 66 + 64]};
        w0d1v[jp] = f32x2{w0[(q * 8 + 2 * jp) * 66 + 65], w0[(q * 8 + 2 * jp + 1) * 66 + 65]};
    }
    // layer-4 weights per D3 row ch3 = q*4+r (rows >=8 are exact zeros)
    float w3c[4];
#pragma unroll
    for (int r = 0; r < 4; r++) w3c[r] = (q < 2) ? w3[q * 4 + r] : 0.f;

    // per-lane distance operand values (pixel phase xm = w%4; ym wave-uniform)
    const int xm = m16 & 3;
    const float xv = (float)(xm < 2 ? xm - 2 : xm - 1);
    const float x1 = (float)(4 - xm), x2 = (float)(xm + 1);
    const int ym = h & 3;
    const float yv = (float)(ym < 2 ? ym - 2 : ym - 1);
    const float y1 = (float)(4 - ym), y2 = (float)(ym + 1);

    _Float16* sa = s_ahr[ty];

    __syncthreads();  // s_alr staged (everything else is per-wave)

    const float* hp = hr + (size_t)b * CC * HW + (size_t)h * WW + wp0;

    // ---- Phase A, both tiles: ahr = hr . w0hr via 4 MFMAs (D[px][ch]) ----
    f16x8 aT0, aT1;
#pragma unroll
    for (int j = 0; j < 8; j++) {
        aT0[j] = (_Float16)hp[(size_t)(q * 8 + j) * HW + m16];
        aT1[j] = (_Float16)hp[(size_t)(q * 8 + j) * HW + 16 + m16];
    }
    {
        f32x4 p00 = {0.f, 0.f, 0.f, 0.f}, p01 = {0.f, 0.f, 0.f, 0.f};
        f32x4 p10 = {0.f, 0.f, 0.f, 0.f}, p11 = {0.f, 0.f, 0.f, 0.f};
        p00 = __builtin_amdgcn_mfma_f32_16x16x32_f16(aT0, w0hB0, p00, 0, 0, 0);
        p01 = __builtin_amdgcn_mfma_f32_16x16x32_f16(aT0, w0hB1, p01, 0, 0, 0);
        p10 = __builtin_amdgcn_mfma_f32_16x16x32_f16(aT1, w0hB0, p10, 0, 0, 0);
        p11 = __builtin_amdgcn_mfma_f32_16x16x32_f16(aT1, w0hB1, p11, 0, 0, 0);
#pragma unroll
        for (int r = 0; r < 4; r++) {
            const int row = q * 4 + r;
            sa[row * 40 + m16] = (_Float16)p00[r];
            sa[row * 40 + 16 + m16] = (_Float16)p01[r];
            sa[(16 + row) * 40 + m16] = (_Float16)p10[r];
            sa[(16 + row) * 40 + 16 + m16] = (_Float16)p11[r];
        }
    }
    // hoist ahr to f32 registers ONCE per tile (reused by all 9 directions)
    const f16x8 ahv0 = *(const f16x8*)&sa[m16 * 40 + q * 8];
    const f16x8 ahv1 = *(const f16x8*)&sa[(16 + m16) * 40 + q * 8];
    f32x2 ah0[4], ah1[4];
#pragma unroll
    for (int jp = 0; jp < 4; jp++) {
        ah0[jp] = f32x2{(float)ahv0[2 * jp], (float)ahv0[2 * jp + 1]};
        ah1[jp] = f32x2{(float)ahv1[2 * jp], (float)ahv1[2 * jp + 1]};
    }

    // alr halo bases per tile (FP32); per-d cell adds a compile-time offset
    // ((1+dh)*10 + (1+dw)) * 40 floats.
    const float* alp0 = &s_alr[(m16 >> 2) * 40 + q * 8];
    const float* alp1 = &s_alr[(4 + (m16 >> 2)) * 40 + q * 8];
    const int wown0 = wp0 + m16;        // this lane's pixel, tile 0 (q-uniform)
    const int wown1 = wp0 + 16 + m16;   // tile 1

    float l0[9], l1[9];
#pragma unroll
    for (int d = 0; d < 9; d++) {
        const int dh = K_dh[d], dw = K_dw[d];
        const float d0 = (K_s0[d] == 0) ? xv : ((K_s0[d] == 1) ? x1 : x2);
        const float d1 = (K_s1[d] == 0) ? yv : ((K_s1[d] == 1) ? y1 : y2);
        const f32x2 d0v = {d0, d0}, d1v = {d1, d1};
        const int off = ((1 + dh) * 10 + (1 + dw)) * 40;

        // shared per-d distance contribution (t-invariant)
        f32x2 dd[4];
#pragma unroll
        for (int jp = 0; jp < 4; jp++)
            dd[jp] = __builtin_elementwise_fma(w0d0v[jp], d0v, w0d1v[jp] * d1v);

        // layer 1 (both tiles): A1[k=ch1][n=px] = leaky(ahr + alr + dd)
        // alr FP32 in LDS: two b128 reads per tile, no cvt chain.
        const f32x2* al0 = (const f32x2*)(alp0 + off);
        const f32x2* al1 = (const f32x2*)(alp1 + off);
        f16x8 a1_0, a1_1;
#pragma unroll
        for (int jp = 0; jp < 4; jp++) {
            f32x2 v0 = ah0[jp] + al0[jp];
            f32x2 v1 = ah1[jp] + al1[jp];
            v0 = v0 + dd[jp];
            v1 = v1 + dd[jp];
            v0 = __builtin_elementwise_max(v0, v0 * 0.01f);
            v1 = __builtin_elementwise_max(v1, v1 * 0.01f);
            a1_0[2 * jp] = (_Float16)v0[0];
            a1_0[2 * jp + 1] = (_Float16)v0[1];
            a1_1[2 * jp] = (_Float16)v1[0];
            a1_1[2 * jp + 1] = (_Float16)v1[1];
        }
        // layer 2 SWAPPED: D2[ch2][px] (lane: rows ch2=q*4+r, col px=m16)
        f32x4 c2_0 = {0.f, 0.f, 0.f, 0.f}, c2_1 = {0.f, 0.f, 0.f, 0.f};
        c2_0 = __builtin_amdgcn_mfma_f32_16x16x32_f16(w1B, a1_0, c2_0, 0, 0, 0);
        c2_1 = __builtin_amdgcn_mfma_f32_16x16x32_f16(w1B, a1_1, c2_1, 0, 0, 0);

        // layer2->3 glue: pure in-lane. D2 rows ch2=q*4+r ARE the 16x16x16
        // B-frag k-rows (k=q*4+r) -> b3 = pack(leaky(c2)).
        f16x4 b3_0, b3_1;
#pragma unroll
        for (int r = 0; r < 4; r++) {
            const float e0 = fmaxf(c2_0[r], 0.01f * c2_0[r]);
            const float e1 = fmaxf(c2_1[r], 0.01f * c2_1[r]);
            b3_0[r] = (_Float16)e0;
            b3_1[r] = (_Float16)e1;
        }
        // layer 3 (16x16x16, K=ch2=16 exact): D3[ch3=q*4+r][px=m16];
        // rows ch3>=8 exact 0 (w2A rows zero)
        f32x4 c3_0 = {0.f, 0.f, 0.f, 0.f}, c3_1 = {0.f, 0.f, 0.f, 0.f};
        c3_0 = __builtin_amdgcn_mfma_f32_16x16x16f16(w2A, b3_0, c3_0, 0, 0, 0);
        c3_1 = __builtin_amdgcn_mfma_f32_16x16x16f16(w2A, b3_1, c3_1, 0, 0, 0);

        // layer 4: in-lane fma over ch3=q*4+r, then sum the 4 q-partials
        // (lanes m16+16q) with swz(x16) + shfl(x32) — the R9-proven reduce.
        {
            float part = 0.f;
#pragma unroll
            for (int r = 0; r < 4; r++) {
                const float lv = fmaxf(c3_0[r], 0.01f * c3_0[r]);
                part = fmaf(w3c[r], lv, part);
            }
            float s2 = part + swz_x16(part);
            const float lg = s2 + __shfl_xor(s2, 32, 64);
            const bool ok = ((unsigned)(h + 4 * dh) < (unsigned)HH) &&
                            ((unsigned)(wown0 + 4 * dw) < (unsigned)WW);
            l0[d] = ok ? lg : -100.0f;
        }
        {
            float part = 0.f;
#pragma unroll
            for (int r = 0; r < 4; r++) {
                const float lv = fmaxf(c3_1[r], 0.01f * c3_1[r]);
                part = fmaf(w3c[r], lv, part);
            }
            float s2 = part + swz_x16(part);
            const float lg = s2 + __shfl_xor(s2, 32, 64);
            const bool ok = ((unsigned)(h + 4 * dh) < (unsigned)HH) &&
                            ((unsigned)(wown1 + 4 * dw) < (unsigned)WW);
            l1[d] = ok ? lg : -100.0f;
        }
    }

    // softmax per tile (R9's proven tails; lane owns px=m16); writers lane<16
    {
        float mx = l0[0];
#pragma unroll
        for (int d = 1; d < 9; d++) mx = fmaxf(mx, l0[d]);
        float s = 0.f;
#pragma unroll
        for (int d = 0; d < 9; d++) {
            l0[d] = __expf(l0[d] - mx);
            s += l0[d];
        }
        const float inv = __builtin_amdgcn_rcpf(s);
        if (lane < 16) {
            float* op = out + (size_t)b * 9 * HW + (size_t)h * WW + wown0;
#pragma unroll
            for (int d = 0; d < 9; d++) op[(size_t)d * HW] = l0[d] * inv;
        }
    }
    {
        float mx = l1[0];
#pragma unroll
        for (int d = 1; d < 9; d++) mx = fmaxf(mx, l1[d]);
        float s = 0.f;
#pragma unroll
        for (int d = 0; d < 9; d++) {
            l1[d] = __expf(l1[d] - mx);
            s += l1[d];
        }
        const float inv = __builtin_amdgcn_rcpf(s);
        if (lane < 16) {
            float* op = out + (size_t)b * 9 * HW + (size_t)h * WW + wown1;
#pragma unroll
            for (int d = 0; d < 9; d++) op[(size_t)d * HW] = l1[d] * inv;
        }
    }
}

extern "C" void kernel_launch(void* const* d_in, const int* in_sizes, int n_in,
                              void* d_out, int out_size, void* d_ws, size_t ws_size,
                              hipStream_t stream) {
    const float* lr = (const float*)d_in[0];
    const float* hr = (const float*)d_in[1];
    // d_in[2], d_in[3] (lr_feature_r / hr_feature_r) are unused by the reference.
    const float* w0 = (const float*)d_in[4];
    const float* w1 = (const float*)d_in[5];
    const float* w2 = (const float*)d_in[6];
    const float* w3 = (const float*)d_in[7];
    float* out = (float*)d_out;

    const size_t alr_bytes = (size_t)BB * CH * CW * 32 * sizeof(float);  // 2 MB
    dim3 grid(WW / 32, HH / 4, BB);  // 2048 blocks of 256 thr (4 waves)

    if (ws_size >= alr_bytes) {
        float* alr = (float*)d_ws;
        alr_prepass<<<(BB * CH * CW + 255) / 256, 256, 0, stream>>>(lr, w0, alr);
        ercm_mfma<true><<<grid, 256, 0, stream>>>(hr, lr, alr, w0, w1, w2, w3, out);
    } else {
        ercm_mfma<false><<<grid, 256, 0, stream>>>(hr, lr, nullptr, w0, w1, w2, w3, out);
    }
}

// Round 13
// 139.337 us; speedup vs baseline: 1.1014x; 1.0123x over previous
//
#include <hip/hip_runtime.h>
#include <math.h>

#define SC 4
#define BB 2
#define CC 32
#define HH 256
#define WW 512
#define CH (HH / SC)   // 64
#define CW (WW / SC)   // 128

using f16x8 = __attribute__((ext_vector_type(8))) _Float16;
using f16x4 = __attribute__((ext_vector_type(4))) _Float16;
using f32x4 = __attribute__((ext_vector_type(4))) float;
using f32x2 = __attribute__((ext_vector_type(2))) float;

// Direction metadata (output channel order: c, l, r, t, b, lt, rt, lb, rb)
//   s0: 0 -> xv (x[w%4]), 1 -> 4-(w%4) (D1), 2 -> (w%4)+1 (D2)
//   s1: 0 -> yv (x[h%4]), 1 -> 4-(h%4) (D3), 2 -> (h%4)+1 (D4)
constexpr int K_dh[9] = {0, 0, 0, -1, 1, -1, -1, 1, 1};
constexpr int K_dw[9] = {0, -1, 1, 0, 0, -1, 1, -1, 1};
constexpr int K_s0[9] = {0, 1, 2, 0, 0, 1, 2, 0, 0};
constexpr int K_s1[9] = {0, 0, 0, 1, 2, 0, 0, 1, 2};

__device__ __forceinline__ float swz_x16(float v) {
    // lane ^ 16 within each 32-lane half: BitMode offset = (16<<10)|0x1F
    return __int_as_float(__builtin_amdgcn_ds_swizzle(__float_as_int(v), 0x401F));
}

// LESSON (R10/R11/R12 bisect): the permlane-swap inline asm
//   asm("v_permlane16_swap_b32 %0, %1" : "+v"(a), "+v"(b))
// with a==b on input can be register-COALESCED by the allocator into a
// self-swap (wrong sums). It passed in R7 and silently broke in R10/R11
// (absmax 1.0) purely from allocation context. R12 (DS reduce, f32 s_alr)
// passed -> the f32 staging is good and the DS reduce below is the proven
// path. Its replication guarantee: swz_x16 gives every lane part+part^16;
// shfl_xor(.,32) adds the other half -> ALL 64 lanes hold the full sum.

// Pre-pass: ALr[(b*CH+cy)*CW+cx][o] = sum_c w0[o*66+c] * lr[b][c][cy][cx]  (fp32)
__global__ __launch_bounds__(256) void alr_prepass(const float* __restrict__ lr,
                                                   const float* __restrict__ w0,
                                                   float* __restrict__ alr) {
    const int idx = blockIdx.x * 256 + threadIdx.x;
    if (idx >= BB * CH * CW) return;
    const int b = idx / (CH * CW);
    const int cell = idx - b * (CH * CW);
    const float* lp = lr + (size_t)b * CC * CH * CW + cell;
    float lv[32];
#pragma unroll
    for (int c = 0; c < 32; c++) lv[c] = lp[(size_t)c * (CH * CW)];
    float acc[32];
#pragma unroll
    for (int o = 0; o < 32; o++) {
        float a = 0.f;
#pragma unroll
        for (int c = 0; c < 32; c++) a = fmaf(lv[c], w0[o * 66 + c], a);
        acc[o] = a;
    }
    float4* op = (float4*)(alr + (size_t)idx * 32);
#pragma unroll
    for (int j = 0; j < 8; j++)
        op[j] = make_float4(acc[4 * j], acc[4 * j + 1], acc[4 * j + 2], acc[4 * j + 3]);
}

// MFMA main, R13 = R12 (PASSING, dur 141.0) + fused tail re-landed.
// R12's bisect proved the R10 failure was xsum64's asm coalescing, NOT the
// fused tail. With the DS reduce, logits are replicated in ALL 64 lanes by
// construction, so the tail may select per-lane:
//   ld = (lane&16) ? l1 : l0   (lanes 0..15 own tile0 px, 16..31 tile1 px)
// -> ONE softmax chain (9 exp not 18), stores from lanes 0..31 = 9
// contiguous 128B stores (was 18 half-wave 64B). Output bit-identical to
// R12 (same logits, same per-pixel arithmetic, replicated lanes).
// Everything else identical to R12: dual-tile (2048 blocks, 256 thr,
// 4 waves, 32 px/wave), f32 s_alr, swapped layer-2 (D2[ch2][px]), in-lane
// K16 layer-3 (v_mfma_f32_16x16x16f16, w2A rows>=8 zero).
// R3 lesson: __launch_bounds__(256,4) (128-VGPR cap), never force 8/EU.
// R7 lesson: no quad-tile. R10 lesson: no aliasable multi-output asm.
template <bool USE_WS>
__global__ __launch_bounds__(256, 4) void ercm_mfma(const float* __restrict__ hr,
                                                    const float* __restrict__ lr,
                                                    const float* __restrict__ alr,
                                                    const float* __restrict__ w0,
                                                    const float* __restrict__ w1,
                                                    const float* __restrict__ w2,
                                                    const float* __restrict__ w3,
                                                    float* __restrict__ out) {
    __shared__ float    s_alr[30 * 40];     // [cell][o] FP32, 3 x 10 halo, stride 40 (160B rows)
    __shared__ _Float16 s_ahr[4][32 * 40];  // per wave: [px 0..31][o] (both tiles)

    const int tid = threadIdx.x;
    const int lane = tid & 63;
    const int ty = tid >> 6;       // wave id = h-row within block
    const int m16 = lane & 15;
    const int q = lane >> 4;       // quad
    const int bx = blockIdx.x;     // 0..15
    const int by = blockIdx.y;     // 0..63
    const int b = blockIdx.z;      // 0..1
    const int h = by * 4 + ty;
    const int wp0 = bx * 32;
    const size_t HW = (size_t)HH * WW;

    // ---- stage ALr halo tile (3 x 10 coarse cells), FP32 ----
    const int cy0 = by, cx0 = bx * 8;
    if (USE_WS) {
        for (int i = tid; i < 30 * 32; i += 256) {
            const int c = i & 31, cell = i >> 5;
            const int row = cell / 10, col = cell - row * 10;
            const int gcy = cy0 - 1 + row, gcx = cx0 - 1 + col;
            float v = 0.f;
            if ((unsigned)gcy < (unsigned)CH && (unsigned)gcx < (unsigned)CW)
                v = alr[(((size_t)b * CH + gcy) * CW + gcx) * 32 + c];
            s_alr[cell * 40 + c] = v;
        }
    } else {
        for (int i = tid; i < 30 * 32; i += 256) {
            const int o = i & 31, cell = i >> 5;
            const int row = cell / 10, col = cell - row * 10;
            const int gcy = cy0 - 1 + row, gcx = cx0 - 1 + col;
            float a = 0.f;
            if ((unsigned)gcy < (unsigned)CH && (unsigned)gcx < (unsigned)CW) {
                const float* lp = lr + (size_t)b * CC * CH * CW + (size_t)gcy * CW + gcx;
#pragma unroll
                for (int c = 0; c < 32; c++) a = fmaf(lp[(size_t)c * (CH * CW)], w0[o * 66 + c], a);
            }
            s_alr[cell * 40 + o] = a;
        }
    }

    // ---- load weight fragments (once). Same lane layout serves A or B. ----
    f16x8 w1B, w0hB0, w0hB1;
    f16x4 w2A;  // 16x16x16 A-frag: [m=ch3=m16][k=ch2=q*4+j], rows>=8 zero
    {
        const float* p1 = w1 + m16 * 32 + q * 8;
        const float* p00 = w0 + m16 * 66 + 32 + q * 8;
        const float* p01 = w0 + (m16 + 16) * 66 + 32 + q * 8;
#pragma unroll
        for (int j = 0; j < 8; j++) {
            w1B[j] = (_Float16)p1[j];
            w0hB0[j] = (_Float16)p00[j];
            w0hB1[j] = (_Float16)p01[j];
        }
        const bool w2ok = (m16 < 8);
#pragma unroll
        for (int j = 0; j < 4; j++)
            w2A[j] = (_Float16)(w2ok ? w2[m16 * 16 + q * 4 + j] : 0.f);
    }
    // layer-1 distance weights for this lane's channels o=q*8+j, as f32x2 pairs
    f32x2 w0d0v[4], w0d1v[4];
#pragma unroll
    for (int jp = 0; jp < 4; jp++) {
        w0d0v[jp] = f32x2{w0[(q * 8 + 2 * jp) * 66 + 64], w0[(q * 8 + 2 * jp + 1) * 66 + 64]};
        w0d1v[jp] = f32x2{w0[(q * 8 + 2 * jp) * 66 + 65], w0[(q * 8 + 2 * jp + 1) * 66 + 65]};
    }
    // layer-4 weights per D3 row ch3 = q*4+r (rows >=8 are exact zeros)
    float w3c[4];
#pragma unroll
    for (int r = 0; r < 4; r++) w3c[r] = (q < 2) ? w3[q * 4 + r] : 0.f;

    // per-lane distance operand values (pixel phase xm = w%4; ym wave-uniform)
    const int xm = m16 & 3;
    const float xv = (float)(xm < 2 ? xm - 2 : xm - 1);
    const float x1 = (float)(4 - xm), x2 = (float)(xm + 1);
    const int ym = h & 3;
    const float yv = (float)(ym < 2 ? ym - 2 : ym - 1);
    const float y1 = (float)(4 - ym), y2 = (float)(ym + 1);

    _Float16* sa = s_ahr[ty];

    __syncthreads();  // s_alr staged (everything else is per-wave)

    const float* hp = hr + (size_t)b * CC * HW + (size_t)h * WW + wp0;

    // ---- Phase A, both tiles: ahr = hr . w0hr via 4 MFMAs (D[px][ch]) ----
    f16x8 aT0, aT1;
#pragma unroll
    for (int j = 0; j < 8; j++) {
        aT0[j] = (_Float16)hp[(size_t)(q * 8 + j) * HW + m16];
        aT1[j] = (_Float16)hp[(size_t)(q * 8 + j) * HW + 16 + m16];
    }
    {
        f32x4 p00 = {0.f, 0.f, 0.f, 0.f}, p01 = {0.f, 0.f, 0.f, 0.f};
        f32x4 p10 = {0.f, 0.f, 0.f, 0.f}, p11 = {0.f, 0.f, 0.f, 0.f};
        p00 = __builtin_amdgcn_mfma_f32_16x16x32_f16(aT0, w0hB0, p00, 0, 0, 0);
        p01 = __builtin_amdgcn_mfma_f32_16x16x32_f16(aT0, w0hB1, p01, 0, 0, 0);
        p10 = __builtin_amdgcn_mfma_f32_16x16x32_f16(aT1, w0hB0, p10, 0, 0, 0);
        p11 = __builtin_amdgcn_mfma_f32_16x16x32_f16(aT1, w0hB1, p11, 0, 0, 0);
#pragma unroll
        for (int r = 0; r < 4; r++) {
            const int row = q * 4 + r;
            sa[row * 40 + m16] = (_Float16)p00[r];
            sa[row * 40 + 16 + m16] = (_Float16)p01[r];
            sa[(16 + row) * 40 + m16] = (_Float16)p10[r];
            sa[(16 + row) * 40 + 16 + m16] = (_Float16)p11[r];
        }
    }
    // hoist ahr to f32 registers ONCE per tile (reused by all 9 directions)
    const f16x8 ahv0 = *(const f16x8*)&sa[m16 * 40 + q * 8];
    const f16x8 ahv1 = *(const f16x8*)&sa[(16 + m16) * 40 + q * 8];
    f32x2 ah0[4], ah1[4];
#pragma unroll
    for (int jp = 0; jp < 4; jp++) {
        ah0[jp] = f32x2{(float)ahv0[2 * jp], (float)ahv0[2 * jp + 1]};
        ah1[jp] = f32x2{(float)ahv1[2 * jp], (float)ahv1[2 * jp + 1]};
    }

    // alr halo bases per tile (FP32); per-d cell adds a compile-time offset
    // ((1+dh)*10 + (1+dw)) * 40 floats.
    const float* alp0 = &s_alr[(m16 >> 2) * 40 + q * 8];
    const float* alp1 = &s_alr[(4 + (m16 >> 2)) * 40 + q * 8];
    const int wown0 = wp0 + m16;        // this lane's pixel, tile 0 (q-uniform)
    const int wown1 = wp0 + 16 + m16;   // tile 1

    float l0[9], l1[9];
#pragma unroll
    for (int d = 0; d < 9; d++) {
        const int dh = K_dh[d], dw = K_dw[d];
        const float d0 = (K_s0[d] == 0) ? xv : ((K_s0[d] == 1) ? x1 : x2);
        const float d1 = (K_s1[d] == 0) ? yv : ((K_s1[d] == 1) ? y1 : y2);
        const f32x2 d0v = {d0, d0}, d1v = {d1, d1};
        const int off = ((1 + dh) * 10 + (1 + dw)) * 40;

        // shared per-d distance contribution (t-invariant)
        f32x2 dd[4];
#pragma unroll
        for (int jp = 0; jp < 4; jp++)
            dd[jp] = __builtin_elementwise_fma(w0d0v[jp], d0v, w0d1v[jp] * d1v);

        // layer 1 (both tiles): A1[k=ch1][n=px] = leaky(ahr + alr + dd)
        // alr FP32 in LDS: two b128 reads per tile, no cvt chain.
        const f32x2* al0 = (const f32x2*)(alp0 + off);
        const f32x2* al1 = (const f32x2*)(alp1 + off);
        f16x8 a1_0, a1_1;
#pragma unroll
        for (int jp = 0; jp < 4; jp++) {
            f32x2 v0 = ah0[jp] + al0[jp];
            f32x2 v1 = ah1[jp] + al1[jp];
            v0 = v0 + dd[jp];
            v1 = v1 + dd[jp];
            v0 = __builtin_elementwise_max(v0, v0 * 0.01f);
            v1 = __builtin_elementwise_max(v1, v1 * 0.01f);
            a1_0[2 * jp] = (_Float16)v0[0];
            a1_0[2 * jp + 1] = (_Float16)v0[1];
            a1_1[2 * jp] = (_Float16)v1[0];
            a1_1[2 * jp + 1] = (_Float16)v1[1];
        }
        // layer 2 SWAPPED: D2[ch2][px] (lane: rows ch2=q*4+r, col px=m16)
        f32x4 c2_0 = {0.f, 0.f, 0.f, 0.f}, c2_1 = {0.f, 0.f, 0.f, 0.f};
        c2_0 = __builtin_amdgcn_mfma_f32_16x16x32_f16(w1B, a1_0, c2_0, 0, 0, 0);
        c2_1 = __builtin_amdgcn_mfma_f32_16x16x32_f16(w1B, a1_1, c2_1, 0, 0, 0);

        // layer2->3 glue: pure in-lane. D2 rows ch2=q*4+r ARE the 16x16x16
        // B-frag k-rows (k=q*4+r) -> b3 = pack(leaky(c2)).
        f16x4 b3_0, b3_1;
#pragma unroll
        for (int r = 0; r < 4; r++) {
            const float e0 = fmaxf(c2_0[r], 0.01f * c2_0[r]);
            const float e1 = fmaxf(c2_1[r], 0.01f * c2_1[r]);
            b3_0[r] = (_Float16)e0;
            b3_1[r] = (_Float16)e1;
        }
        // layer 3 (16x16x16, K=ch2=16 exact): D3[ch3=q*4+r][px=m16];
        // rows ch3>=8 exact 0 (w2A rows zero)
        f32x4 c3_0 = {0.f, 0.f, 0.f, 0.f}, c3_1 = {0.f, 0.f, 0.f, 0.f};
        c3_0 = __builtin_amdgcn_mfma_f32_16x16x16f16(w2A, b3_0, c3_0, 0, 0, 0);
        c3_1 = __builtin_amdgcn_mfma_f32_16x16x16f16(w2A, b3_1, c3_1, 0, 0, 0);

        // layer 4: in-lane fma over ch3=q*4+r, then sum the 4 q-partials
        // (lanes m16+16q) with swz(x16) + shfl(x32) — proven reduce; result
        // replicated in ALL 64 lanes by construction.
        {
            float part = 0.f;
#pragma unroll
            for (int r = 0; r < 4; r++) {
                const float lv = fmaxf(c3_0[r], 0.01f * c3_0[r]);
                part = fmaf(w3c[r], lv, part);
            }
            float s2 = part + swz_x16(part);
            const float lg = s2 + __shfl_xor(s2, 32, 64);
            const bool ok = ((unsigned)(h + 4 * dh) < (unsigned)HH) &&
                            ((unsigned)(wown0 + 4 * dw) < (unsigned)WW);
            l0[d] = ok ? lg : -100.0f;
        }
        {
            float part = 0.f;
#pragma unroll
            for (int r = 0; r < 4; r++) {
                const float lv = fmaxf(c3_1[r], 0.01f * c3_1[r]);
                part = fmaf(w3c[r], lv, part);
            }
            float s2 = part + swz_x16(part);
            const float lg = s2 + __shfl_xor(s2, 32, 64);
            const bool ok = ((unsigned)(h + 4 * dh) < (unsigned)HH) &&
                            ((unsigned)(wown1 + 4 * dw) < (unsigned)WW);
            l1[d] = ok ? lg : -100.0f;
        }
    }

    // fused tail: logits are replicated in all 64 lanes (DS reduce), so each
    // lane selects its own pixel's 9 logits and runs ONE softmax chain.
    // lanes 0..15 -> tile0 px wp0+lane; lanes 16..31 -> tile1 px wp0+lane.
    float ld[9];
#pragma unroll
    for (int d = 0; d < 9; d++) ld[d] = (lane & 16) ? l1[d] : l0[d];
    float mx = ld[0];
#pragma unroll
    for (int d = 1; d < 9; d++) mx = fmaxf(mx, ld[d]);
    float s = 0.f;
#pragma unroll
    for (int d = 0; d < 9; d++) {
        ld[d] = __expf(ld[d] - mx);
        s += ld[d];
    }
    const float inv = __builtin_amdgcn_rcpf(s);
    if (lane < 32) {  // 32 writer lanes -> 9 contiguous 128B stores (both tiles)
        float* op = out + (size_t)b * 9 * HW + (size_t)h * WW + (wp0 + lane);
#pragma unroll
        for (int d = 0; d < 9; d++) op[(size_t)d * HW] = ld[d] * inv;
    }
}

extern "C" void kernel_launch(void* const* d_in, const int* in_sizes, int n_in,
                              void* d_out, int out_size, void* d_ws, size_t ws_size,
                              hipStream_t stream) {
    const float* lr = (const float*)d_in[0];
    const float* hr = (const float*)d_in[1];
    // d_in[2], d_in[3] (lr_feature_r / hr_feature_r) are unused by the reference.
    const float* w0 = (const float*)d_in[4];
    const float* w1 = (const float*)d_in[5];
    const float* w2 = (const float*)d_in[6];
    const float* w3 = (const float*)d_in[7];
    float* out = (float*)d_out;

    const size_t alr_bytes = (size_t)BB * CH * CW * 32 * sizeof(float);  // 2 MB
    dim3 grid(WW / 32, HH / 4, BB);  // 2048 blocks of 256 thr (4 waves)

    if (ws_size >= alr_bytes) {
        float* alr = (float*)d_ws;
        alr_prepass<<<(BB * CH * CW + 255) / 256, 256, 0, stream>>>(lr, w0, alr);
        ercm_mfma<true><<<grid, 256, 0, stream>>>(hr, lr, alr, w0, w1, w2, w3, out);
    } else {
        ercm_mfma<false><<<grid, 256, 0, stream>>>(hr, lr, nullptr, w0, w1, w2, w3, out);
    }
}